// Round 1
// baseline (13551.787 us; speedup 1.0000x reference)
//
#include <hip/hip_runtime.h>
#include <math.h>

// TGCN: B=16, T=12, N=1000, H=128, NL=2
#define BB 16
#define TT 12
#define NN 1000
#define HH 128
#define CC 129            // H+1
#define BC 2064           // BB*CC
#define G2 256            // 2H
#define NROW 16000        // BB*NN

__device__ __forceinline__ float sigmoidf_(float x) { return 1.0f / (1.0f + expf(-x)); }

// ---------------- laplacian ----------------
__global__ void k_softmax(const float* __restrict__ adj, float* __restrict__ a) {
    int i = blockIdx.x;
    int t = threadIdx.x;
    __shared__ float red[256];
    float m = -1e30f;
    for (int j = t; j < NN; j += 256) m = fmaxf(m, adj[i * NN + j]);
    red[t] = m; __syncthreads();
    for (int s = 128; s > 0; s >>= 1) { if (t < s) red[t] = fmaxf(red[t], red[t + s]); __syncthreads(); }
    m = red[0]; __syncthreads();
    float sum = 0.f;
    for (int j = t; j < NN; j += 256) sum += expf(adj[i * NN + j] - m);
    red[t] = sum; __syncthreads();
    for (int s = 128; s > 0; s >>= 1) { if (t < s) red[t] += red[t + s]; __syncthreads(); }
    float inv = 1.0f / red[0];
    for (int j = t; j < NN; j += 256) a[i * NN + j] = expf(adj[i * NN + j] - m) * inv;
}

// L[i][j] = 0.5*(a[j][i] + (i==j))   (row sums of softmax are 1 -> d==2 -> dis=2^-0.5)
__global__ void k_build_L(const float* __restrict__ a, float* __restrict__ L) {
    int idx = blockIdx.x * 256 + threadIdx.x;
    if (idx >= NN * NN) return;
    int i = idx / NN, j = idx % NN;
    L[idx] = 0.5f * (a[j * NN + i] + (i == j ? 1.0f : 0.0f));
}

// ---------------- per-timestep prep ----------------
__global__ void k_copy_x(const float* __restrict__ inp, float* __restrict__ x, int t) {
    int idx = blockIdx.x * 256 + threadIdx.x;
    if (idx >= NROW) return;
    int b = idx / NN, n = idx % NN;
    x[idx] = inp[(b * TT + t) * NN + n];
}

// concatA[n][b*129+c] = (c==0 ? x[b][n] : h[b][n][c-1]); also concatB col0 = x
__global__ void k_build_concat(const float* __restrict__ x, const float* __restrict__ h,
                               float* __restrict__ cA, float* __restrict__ cB) {
    int idx = blockIdx.x * 256 + threadIdx.x;
    if (idx >= NN * BC) return;
    int n = idx / BC;
    int r = idx % BC;
    int b = r / CC, c = r % CC;
    float v;
    if (c == 0) { v = x[b * NN + n]; cB[idx] = v; }
    else v = h[(b * NN + n) * HH + (c - 1)];
    cA[idx] = v;
}

// ---------------- GEMM: C[1000 x 2064] = L[1000x1000] @ X[1000x2064] (f32) ----------------
// BM=64, BN=128, BK=8, 256 threads, micro-tile 4x8
__global__ __launch_bounds__(256) void k_gemm_L(const float* __restrict__ A,
                                                const float* __restrict__ Bm,
                                                float* __restrict__ Cm) {
    __shared__ float sA[8][68];    // [k][m] transposed, padded
    __shared__ float sB[8][128];
    int tid = threadIdx.x;
    int bm = blockIdx.y * 64;
    int bn = blockIdx.x * 128;
    int ty = tid >> 4;   // 0..15 (rows)
    int tx = tid & 15;   // 0..15 (cols)

    float acc[4][8];
#pragma unroll
    for (int i = 0; i < 4; i++)
#pragma unroll
        for (int j = 0; j < 8; j++) acc[i][j] = 0.f;

    int mlA = tid >> 2;          // 0..63
    int k2A = (tid & 3) * 2;     // 0,2,4,6
    int rB = tid >> 5;           // 0..7
    int cB4 = (tid & 31) * 4;    // 0..124

    for (int bk = 0; bk < 1000; bk += 8) {
        // A tile 64x8
        float2 av = make_float2(0.f, 0.f);
        int gm = bm + mlA;
        if (gm < NN) av = *(const float2*)&A[gm * 1000 + bk + k2A];
        sA[k2A][mlA] = av.x;
        sA[k2A + 1][mlA] = av.y;
        // B tile 8x128
        float4 bv = make_float4(0.f, 0.f, 0.f, 0.f);
        int gc = bn + cB4;
        if (gc < BC) bv = *(const float4*)&Bm[(bk + rB) * BC + gc];
        *(float4*)&sB[rB][cB4] = bv;
        __syncthreads();

#pragma unroll
        for (int k = 0; k < 8; k++) {
            float4 a0 = *(float4*)&sA[k][ty * 4];
            float4 b0 = *(float4*)&sB[k][tx * 8];
            float4 b1 = *(float4*)&sB[k][tx * 8 + 4];
            float ar[4] = {a0.x, a0.y, a0.z, a0.w};
            float br[8] = {b0.x, b0.y, b0.z, b0.w, b1.x, b1.y, b1.z, b1.w};
#pragma unroll
            for (int i = 0; i < 4; i++)
#pragma unroll
                for (int j = 0; j < 8; j++) acc[i][j] += ar[i] * br[j];
        }
        __syncthreads();
    }

#pragma unroll
    for (int i = 0; i < 4; i++) {
        int gm = bm + ty * 4 + i;
        if (gm >= NN) continue;
        int gc = bn + tx * 8;
        if (gc < BC) {
            float4 o0 = make_float4(acc[i][0], acc[i][1], acc[i][2], acc[i][3]);
            float4 o1 = make_float4(acc[i][4], acc[i][5], acc[i][6], acc[i][7]);
            *(float4*)&Cm[gm * BC + gc] = o0;
            *(float4*)&Cm[gm * BC + gc + 4] = o1;
        }
    }
}

// ---------------- gates: sigmoid(ac@w1+b1) with flat-chunk scatter ----------------
// block: 16 rows of (b*N+n), 256 threads (one per output col o)
__global__ __launch_bounds__(256) void k_gates(const float* __restrict__ ac,
                                               const float* __restrict__ w1,
                                               const float* __restrict__ b1,
                                               const float* __restrict__ h,
                                               float* __restrict__ cB,
                                               float* __restrict__ u) {
    __shared__ float s_ac[16][132];
    int row0 = blockIdx.x * 16;
    int t = threadIdx.x;
    for (int q = t; q < 16 * CC; q += 256) {
        int r = q / CC, c = q % CC;
        int row = row0 + r;
        int rb = row / NN, rn = row % NN;
        s_ac[r][c] = ac[rn * BC + rb * CC + c];
    }
    __syncthreads();
    int o = t;
    float acc[16];
#pragma unroll
    for (int r = 0; r < 16; r++) acc[r] = 0.f;
    for (int c = 0; c < CC; c++) {
        float w = w1[c * G2 + o];
#pragma unroll
        for (int r = 0; r < 16; r++) acc[r] += s_ac[r][c] * w;
    }
    float bias = b1[o];
    int j = o & 127;
    int hi = (o >= 128) ? 1 : 0;
#pragma unroll
    for (int r = 0; r < 16; r++) {
        int row = row0 + r;
        int rb = row / NN, rn = row % NN;
        float g = sigmoidf_(acc[r] + bias);
        if (rn < 500) {
            int m = 2 * rn + hi;                   // r-gate -> rh into concatB
            cB[m * BC + rb * CC + 1 + j] = g * h[(rb * NN + m) * HH + j];
        } else {
            int m = 2 * (rn - 500) + hi;           // u-gate
            u[(rb * NN + m) * HH + j] = g;
        }
    }
}

// ---------------- cell finish: c=tanh(ac2@w2+b2); h=u*h+(1-u)*c; +res; LN; mean ----------------
// block: 16 rows, 256 threads: j = t&127, half = t>>7 handles rows half*8..half*8+7
__global__ __launch_bounds__(256) void k_cellfinish(const float* __restrict__ ac2,
                                                    const float* __restrict__ w2,
                                                    const float* __restrict__ b2,
                                                    const float* __restrict__ u,
                                                    float* __restrict__ h,
                                                    const float* __restrict__ x_in,
                                                    const float* __restrict__ res_w,
                                                    const float* __restrict__ res_b,
                                                    const float* __restrict__ ln_g,
                                                    const float* __restrict__ ln_b,
                                                    float* __restrict__ x_out,
                                                    float* __restrict__ out_t,
                                                    int store_out) {
    __shared__ float s_ac[16][132];
    __shared__ float s_y[16][128];
    __shared__ float s_stat[16][2];
    int row0 = blockIdx.x * 16;
    int t = threadIdx.x;
    for (int q = t; q < 16 * CC; q += 256) {
        int r = q / CC, c = q % CC;
        int row = row0 + r;
        int rb = row / NN, rn = row % NN;
        s_ac[r][c] = ac2[rn * BC + rb * CC + c];
    }
    __syncthreads();
    int j = t & 127, half = t >> 7;
    float acc[8];
#pragma unroll
    for (int r = 0; r < 8; r++) acc[r] = 0.f;
    for (int c = 0; c < CC; c++) {
        float w = w2[c * HH + j];
#pragma unroll
        for (int r = 0; r < 8; r++) acc[r] += s_ac[half * 8 + r][c] * w;
    }
    float bias = b2[j];
    float rw = res_w[j], rbv = res_b[j];
#pragma unroll
    for (int r = 0; r < 8; r++) {
        int rr = half * 8 + r;
        int row = row0 + rr;
        float cv = tanhf(acc[r] + bias);
        float uu = u[row * HH + j];
        float hv = h[row * HH + j];
        float hn = uu * hv + (1.f - uu) * cv;
        h[row * HH + j] = hn;
        s_y[rr][j] = hn + x_in[row] * rw + rbv;
    }
    __syncthreads();
    int wave = t >> 6, lane = t & 63;
    for (int rr = wave; rr < 16; rr += 4) {
        float v1 = s_y[rr][lane], v2 = s_y[rr][lane + 64];
        float s = v1 + v2, ss = v1 * v1 + v2 * v2;
        for (int off = 32; off > 0; off >>= 1) { s += __shfl_down(s, off); ss += __shfl_down(ss, off); }
        if (lane == 0) {
            float mu = s * (1.f / 128.f);
            float var = ss * (1.f / 128.f) - mu * mu;
            s_stat[rr][0] = mu;
            s_stat[rr][1] = rsqrtf(var + 1e-5f);
        }
    }
    __syncthreads();
    float lg = ln_g[j], lb = ln_b[j];
    float outv[8];
#pragma unroll
    for (int r = 0; r < 8; r++) {
        int rr = half * 8 + r;
        outv[r] = (s_y[rr][j] - s_stat[rr][0]) * s_stat[rr][1] * lg + lb;
    }
    __syncthreads();
#pragma unroll
    for (int r = 0; r < 8; r++) s_y[half * 8 + r][j] = outv[r];
    __syncthreads();
    for (int rr = wave; rr < 16; rr += 4) {
        float v = s_y[rr][lane] + s_y[rr][lane + 64];
        for (int off = 32; off > 0; off >>= 1) v += __shfl_down(v, off);
        if (lane == 0) x_out[row0 + rr] = v * (1.f / 128.f);
    }
    if (store_out) {
#pragma unroll
        for (int r = 0; r < 8; r++) {
            int rr = half * 8 + r;
            out_t[(row0 + rr) * HH + j] = outv[r];
        }
    }
}

// ---------------- fused GRU cell (one timestep) ----------------
// block: 128 threads, 8 rows; thread t owns gate columns t, t+128, t+256
__global__ __launch_bounds__(128) void k_gru(const float* __restrict__ xin,
                                             float* __restrict__ hg,
                                             const float* __restrict__ wih,
                                             const float* __restrict__ whh,
                                             const float* __restrict__ bih,
                                             const float* __restrict__ bhh) {
    __shared__ float s_x[8][128];
    __shared__ float s_h[8][128];
    int row0 = blockIdx.x * 8;
    int t = threadIdx.x;
    for (int q = t; q < 8 * HH; q += 128) {
        int r = q >> 7, c = q & 127;
        s_x[r][c] = xin[(row0 + r) * HH + c];
        s_h[r][c] = hg[(row0 + r) * HH + c];
    }
    __syncthreads();
    float gi0[8], gi1[8], gi2[8], gh0[8], gh1[8], gh2[8];
#pragma unroll
    for (int r = 0; r < 8; r++) { gi0[r]=gi1[r]=gi2[r]=gh0[r]=gh1[r]=gh2[r]=0.f; }
    for (int c = 0; c < HH; c++) {
        float wi0 = wih[t * HH + c], wi1 = wih[(t + 128) * HH + c], wi2 = wih[(t + 256) * HH + c];
        float wh0 = whh[t * HH + c], wh1 = whh[(t + 128) * HH + c], wh2 = whh[(t + 256) * HH + c];
#pragma unroll
        for (int r = 0; r < 8; r++) {
            float xv = s_x[r][c], hv = s_h[r][c];
            gi0[r] += xv * wi0; gi1[r] += xv * wi1; gi2[r] += xv * wi2;
            gh0[r] += hv * wh0; gh1[r] += hv * wh1; gh2[r] += hv * wh2;
        }
    }
    float bi0 = bih[t], bi1 = bih[t + 128], bi2 = bih[t + 256];
    float bh0 = bhh[t], bh1 = bhh[t + 128], bh2 = bhh[t + 256];
#pragma unroll
    for (int r = 0; r < 8; r++) {
        float rg = sigmoidf_(gi0[r] + bi0 + gh0[r] + bh0);
        float zg = sigmoidf_(gi1[r] + bi1 + gh1[r] + bh1);
        float ng = tanhf(gi2[r] + bi2 + rg * (gh2[r] + bh2));
        hg[(row0 + r) * HH + t] = (1.f - zg) * ng + zg * s_h[r][t];
    }
}

// ---------------- head: proj -> relu MLP -> out ----------------
__global__ __launch_bounds__(256) void k_head(const float* __restrict__ hg,
                                              const float* __restrict__ pw,
                                              const float* __restrict__ pb,
                                              const float* __restrict__ w1,
                                              const float* __restrict__ b1,
                                              const float* __restrict__ w2,
                                              const float* __restrict__ b2,
                                              float* __restrict__ out) {
    __shared__ float s_h[16][128];
    __shared__ float s_last[16][128];
    __shared__ float s_hid[16][256];
    int row0 = blockIdx.x * 16;
    int t = threadIdx.x;
    for (int q = t; q < 16 * HH; q += 256) {
        int r = q >> 7, c = q & 127;
        s_h[r][c] = hg[(row0 + r) * HH + c];
    }
    __syncthreads();
    int j = t & 127, half = t >> 7;
    // proj
    float acc[8];
#pragma unroll
    for (int r = 0; r < 8; r++) acc[r] = 0.f;
    for (int c = 0; c < HH; c++) {
        float w = pw[j * HH + c];
#pragma unroll
        for (int r = 0; r < 8; r++) acc[r] += s_h[half * 8 + r][c] * w;
    }
    float pbv = pb[j];
#pragma unroll
    for (int r = 0; r < 8; r++) s_last[half * 8 + r][j] = acc[r] + pbv;
    __syncthreads();
    // hidden = relu(last @ w1.T + b1), o = t (0..255)
    float acc2[16];
#pragma unroll
    for (int r = 0; r < 16; r++) acc2[r] = 0.f;
    for (int c = 0; c < HH; c++) {
        float w = w1[t * HH + c];
#pragma unroll
        for (int r = 0; r < 16; r++) acc2[r] += s_last[r][c] * w;
    }
    float b1v = b1[t];
#pragma unroll
    for (int r = 0; r < 16; r++) s_hid[r][t] = fmaxf(acc2[r] + b1v, 0.f);
    __syncthreads();
    // out = hidden @ w2.T + b2
    float acc3[8];
#pragma unroll
    for (int r = 0; r < 8; r++) acc3[r] = 0.f;
    for (int c = 0; c < 256; c++) {
        float w = w2[j * 256 + c];
#pragma unroll
        for (int r = 0; r < 8; r++) acc3[r] += s_hid[half * 8 + r][c] * w;
    }
    float b2v = b2[j];
#pragma unroll
    for (int r = 0; r < 8; r++) out[(row0 + half * 8 + r) * HH + j] = acc3[r] + b2v;
}

extern "C" void kernel_launch(void* const* d_in, const int* in_sizes, int n_in,
                              void* d_out, int out_size, void* d_ws, size_t ws_size,
                              hipStream_t stream) {
    const float* inp    = (const float*)d_in[0];
    const float* adj    = (const float*)d_in[1];
    const float* gc1_w  = (const float*)d_in[2];
    const float* gc1_b  = (const float*)d_in[3];
    const float* gc2_w  = (const float*)d_in[4];
    const float* gc2_b  = (const float*)d_in[5];
    const float* ln_g   = (const float*)d_in[6];
    const float* ln_b   = (const float*)d_in[7];
    const float* res_w  = (const float*)d_in[8];
    const float* res_b  = (const float*)d_in[9];
    const float* wih    = (const float*)d_in[10];
    const float* whh    = (const float*)d_in[11];
    const float* bih    = (const float*)d_in[12];
    const float* bhh    = (const float*)d_in[13];
    const float* proj_w = (const float*)d_in[14];
    const float* proj_b = (const float*)d_in[15];
    const float* ow1    = (const float*)d_in[16];
    const float* ob1    = (const float*)d_in[17];
    const float* ow2    = (const float*)d_in[18];
    const float* ob2    = (const float*)d_in[19];
    float* out = (float*)d_out;

    float* ws = (float*)d_ws;
    size_t off = 0;
    float* a_sm = ws + off; off += (size_t)NN * NN;       // 1,000,000
    float* L    = ws + off; off += (size_t)NN * NN;       // 1,000,000
    float* cA   = ws + off; off += (size_t)NN * BC;       // 2,064,000
    float* acA  = ws + off; off += (size_t)NN * BC;       // 2,064,000 (reused for ac2)
    float* cB   = ws + off; off += (size_t)NN * BC;       // 2,064,000
    float* u    = ws + off; off += (size_t)NROW * HH;     // 2,048,000
    float* h0   = ws + off; off += (size_t)NROW * HH;
    float* h1   = ws + off; off += (size_t)NROW * HH;
    float* outT = ws + off; off += (size_t)NROW * HH;
    float* hg   = ws + off; off += (size_t)NROW * HH;
    float* xA   = ws + off; off += NROW;
    float* xB   = ws + off; off += NROW;
    // total ~16.4M floats (~66 MB)

    size_t stBytes = (size_t)NROW * HH * sizeof(float);
    hipMemsetAsync(h0, 0, stBytes, stream);
    hipMemsetAsync(h1, 0, stBytes, stream);
    hipMemsetAsync(hg, 0, stBytes, stream);

    k_softmax<<<NN, 256, 0, stream>>>(adj, a_sm);
    k_build_L<<<(NN * NN + 255) / 256, 256, 0, stream>>>(a_sm, L);

    dim3 ggrid(17, 16);
    for (int t = 0; t < TT; t++) {
        k_copy_x<<<(NROW + 255) / 256, 256, 0, stream>>>(inp, xA, t);
        for (int l = 0; l < 2; l++) {
            float* xin  = (l == 0) ? xA : xB;
            float* xout = (l == 0) ? xB : xA;
            float* hbuf = (l == 0) ? h0 : h1;
            k_build_concat<<<(NN * BC + 255) / 256, 256, 0, stream>>>(xin, hbuf, cA, cB);
            k_gemm_L<<<ggrid, 256, 0, stream>>>(L, cA, acA);
            k_gates<<<NROW / 16, 256, 0, stream>>>(acA, gc1_w + (size_t)l * CC * G2,
                                                   gc1_b + (size_t)l * G2, hbuf, cB, u);
            k_gemm_L<<<ggrid, 256, 0, stream>>>(L, cB, acA);
            k_cellfinish<<<NROW / 16, 256, 0, stream>>>(acA, gc2_w + (size_t)l * CC * HH,
                                                        gc2_b + (size_t)l * HH, u, hbuf, xin,
                                                        res_w, res_b, ln_g + (size_t)l * HH,
                                                        ln_b + (size_t)l * HH, xout, outT,
                                                        (l == 1) ? 1 : 0);
        }
        k_gru<<<NROW / 8, 128, 0, stream>>>(outT, hg, wih, whh, bih, bhh);
    }
    k_head<<<NROW / 16, 256, 0, stream>>>(hg, proj_w, proj_b, ow1, ob1, ow2, ob2, out);
}

// Round 2
// 3721.802 us; speedup vs baseline: 3.6412x; 3.6412x over previous
//
#include <hip/hip_runtime.h>
#include <math.h>

// TGCN: B=16, T=12, N=1000, H=128, NL=2
#define BB 16
#define TT 12
#define NN 1000
#define HH 128
#define CC 129            // H+1
#define G2 256            // 2H
#define NROW 16000        // BB*NN
#define KP 1024           // padded K (graph nodes)
#define MP 1024           // padded M (L rows)
#define GRP 2176          // padded G rows (c-index = b*129+c -> 2064, pad to 17*128)

typedef __attribute__((ext_vector_type(4))) float f32x4;
typedef __attribute__((ext_vector_type(8))) __bf16 bf16x8;
typedef __attribute__((ext_vector_type(4))) int int4v;

__device__ __forceinline__ float sigmoidf_(float x) { return 1.0f / (1.0f + expf(-x)); }

// ---------------- laplacian ----------------
__global__ void k_softmax(const float* __restrict__ adj, float* __restrict__ a) {
    int i = blockIdx.x;
    int t = threadIdx.x;
    __shared__ float red[256];
    float m = -1e30f;
    for (int j = t; j < NN; j += 256) m = fmaxf(m, adj[i * NN + j]);
    red[t] = m; __syncthreads();
    for (int s = 128; s > 0; s >>= 1) { if (t < s) red[t] = fmaxf(red[t], red[t + s]); __syncthreads(); }
    m = red[0]; __syncthreads();
    float sum = 0.f;
    for (int j = t; j < NN; j += 256) sum += expf(adj[i * NN + j] - m);
    red[t] = sum; __syncthreads();
    for (int s = 128; s > 0; s >>= 1) { if (t < s) red[t] += red[t + s]; __syncthreads(); }
    float inv = 1.0f / red[0];
    for (int j = t; j < NN; j += 256) a[i * NN + j] = expf(adj[i * NN + j] - m) * inv;
}

// Lb[i][j] = bf16( 0.5*(a[j][i] + (i==j)) ), tiled transpose. Pads stay zero (memset).
__global__ __launch_bounds__(256) void k_build_Lt(const float* __restrict__ a, __bf16* __restrict__ Lb) {
    __shared__ float s[64][65];
    int bi = blockIdx.x * 64;   // i tile (output row m)
    int bj = blockIdx.y * 64;   // j tile (k)
    int t = threadIdx.x;
    for (int q = t; q < 64 * 64; q += 256) {
        int r = q >> 6, c = q & 63;
        int jj = bj + r, ii = bi + c;
        s[r][c] = (jj < NN && ii < NN) ? a[jj * NN + ii] : 0.f;
    }
    __syncthreads();
    for (int q = t; q < 64 * 64; q += 256) {
        int r = q >> 6, c = q & 63;       // r: i-offset, c: j-offset
        int ii = bi + r, jj = bj + c;
        if (ii < NN && jj < NN)
            Lb[(size_t)ii * KP + jj] = (__bf16)(0.5f * (s[c][r] + (ii == jj ? 1.f : 0.f)));
    }
}

// GRU weight transpose: wT[0..][c*384+g]=wih[g*128+c]; wT[49152+ c*384+g]=whh[g*128+c]
__global__ void k_transpose_w(const float* __restrict__ wih, const float* __restrict__ whh,
                              float* __restrict__ wT) {
    int idx = blockIdx.x * 256 + threadIdx.x;
    if (idx >= 128 * 384) return;
    int c = idx & 127, g = idx >> 7;
    wT[c * 384 + g] = wih[g * 128 + c];
    wT[128 * 384 + c * 384 + g] = whh[g * 128 + c];
}

// ---------------- per-timestep x: xA + x-columns of G0 and GB ----------------
__global__ void k_copy_x(const float* __restrict__ inp, float* __restrict__ x,
                         __bf16* __restrict__ g0, __bf16* __restrict__ gb, int t) {
    int idx = blockIdx.x * 256 + threadIdx.x;
    if (idx >= NROW) return;
    int b = idx / NN, n = idx % NN;
    float v = inp[(b * TT + t) * NN + n];
    x[idx] = v;
    __bf16 bv = (__bf16)v;
    g0[(size_t)(b * CC) * KP + n] = bv;
    gb[(size_t)(b * CC) * KP + n] = bv;
}

// ---------------- MFMA GEMM: acT[c][m] = sum_k G[c][k] * Lb[m][k] ----------------
// G: bf16 [GRP][KP], Lb: bf16 [MP][KP], acT: f32 [GRP][MP]
// block 256 (4 waves 2x2), tile 128(c) x 64(m), BK=32. grid (MP/64=16, GRP/128=17)
__global__ __launch_bounds__(256) void k_gemm_mfma(const __bf16* __restrict__ G,
                                                   const __bf16* __restrict__ Lb,
                                                   float* __restrict__ acT) {
    __shared__ __bf16 sG[128 * 40];   // padded stride 40 elems (80B) -> conflict-free
    __shared__ __bf16 sL[64 * 40];
    int tid = threadIdx.x;
    int mb = blockIdx.x * 64;
    int cb = blockIdx.y * 128;
    int wave = tid >> 6, lane = tid & 63;
    int wr = wave >> 1, wc = wave & 1;          // wr: c-half(64), wc: m-half(32)
    int lrow = lane & 15;
    int kgrp = lane >> 4;                        // 0..3
    int srow = tid >> 2;                         // 0..63
    int skoff = (tid & 3) * 8;                   // 0,8,16,24

    f32x4 acc[4][2];
#pragma unroll
    for (int i = 0; i < 4; i++)
#pragma unroll
        for (int j = 0; j < 2; j++) acc[i][j] = (f32x4){0.f, 0.f, 0.f, 0.f};

    const int4v* gp0 = (const int4v*)(G + (size_t)(cb + srow) * KP + skoff);
    const int4v* gp1 = (const int4v*)(G + (size_t)(cb + 64 + srow) * KP + skoff);
    const int4v* lp0 = (const int4v*)(Lb + (size_t)(mb + srow) * KP + skoff);

    for (int kk = 0; kk < KP; kk += 32) {
        int4v g0 = gp0[kk >> 3];
        int4v g1 = gp1[kk >> 3];
        int4v l0 = lp0[kk >> 3];
        __syncthreads();
        *(int4v*)&sG[srow * 40 + skoff] = g0;
        *(int4v*)&sG[(srow + 64) * 40 + skoff] = g1;
        *(int4v*)&sL[srow * 40 + skoff] = l0;
        __syncthreads();

        bf16x8 yf[2];
#pragma unroll
        for (int fy = 0; fy < 2; fy++)
            yf[fy] = *(const bf16x8*)&sL[(wc * 32 + fy * 16 + lrow) * 40 + kgrp * 8];
#pragma unroll
        for (int fx = 0; fx < 4; fx++) {
            bf16x8 xf = *(const bf16x8*)&sG[(wr * 64 + fx * 16 + lrow) * 40 + kgrp * 8];
            acc[fx][0] = __builtin_amdgcn_mfma_f32_16x16x32_bf16(xf, yf[0], acc[fx][0], 0, 0, 0);
            acc[fx][1] = __builtin_amdgcn_mfma_f32_16x16x32_bf16(xf, yf[1], acc[fx][1], 0, 0, 0);
        }
    }

#pragma unroll
    for (int fx = 0; fx < 4; fx++) {
        int rbase = cb + wr * 64 + fx * 16 + kgrp * 4;
#pragma unroll
        for (int fy = 0; fy < 2; fy++) {
            int col = mb + wc * 32 + fy * 16 + lrow;
#pragma unroll
            for (int i = 0; i < 4; i++)
                acT[(size_t)(rbase + i) * MP + col] = acc[fx][fy][i];
        }
    }
}

// ---------------- gates: sigmoid(ac@w1+b1), flat-chunk scatter; rh -> GB (bf16) ----------------
__global__ __launch_bounds__(256) void k_gates(const float* __restrict__ acT,
                                               const float* __restrict__ w1,
                                               const float* __restrict__ b1,
                                               const float* __restrict__ h,
                                               __bf16* __restrict__ GB,
                                               float* __restrict__ u) {
    __shared__ float s_ac[16][132];
    __shared__ float s_rh[32][129];
    int row0 = blockIdx.x * 16;
    int t = threadIdx.x;
    for (int q = t; q < 16 * CC; q += 256) {
        int c = q >> 4, r = q & 15;
        int row = row0 + r;
        int rb = row / NN, rn = row % NN;
        s_ac[r][c] = acT[(size_t)(rb * CC + c) * MP + rn];
    }
    __syncthreads();
    int o = t;
    float acc[16];
#pragma unroll
    for (int r = 0; r < 16; r++) acc[r] = 0.f;
    for (int c = 0; c < CC; c++) {
        float w = w1[c * G2 + o];
#pragma unroll
        for (int r = 0; r < 16; r++) acc[r] += s_ac[r][c] * w;
    }
    float bias = b1[o];
    int j = o & 127;
    int hi = o >> 7;
    int rb0 = row0 / NN, rn0 = row0 % NN;
    bool sameb = (rn0 + 15) < NN;
    bool clean_r = sameb && (rn0 + 15) < 500;
    bool clean_u = sameb && rn0 >= 500;

    if (clean_r) {
        int m0 = 2 * rn0;
#pragma unroll
        for (int r = 0; r < 16; r++) {
            float g = sigmoidf_(acc[r] + bias);
            int m = 2 * (rn0 + r) + hi;
            s_rh[m - m0][j] = g * h[(size_t)(rb0 * NN + m) * HH + j];
        }
        __syncthreads();
        int jj = t >> 1, half = t & 1;
        bf16x8 v0, v1;
#pragma unroll
        for (int q = 0; q < 8; q++) {
            v0[q] = (__bf16)s_rh[half * 16 + q][jj];
            v1[q] = (__bf16)s_rh[half * 16 + 8 + q][jj];
        }
        __bf16* gbp = GB + (size_t)(rb0 * CC + 1 + jj) * KP + m0 + half * 16;
        *(bf16x8*)gbp = v0;
        *(bf16x8*)(gbp + 8) = v1;
    } else if (clean_u) {
#pragma unroll
        for (int r = 0; r < 16; r++) {
            float g = sigmoidf_(acc[r] + bias);
            int m = 2 * (rn0 + r - 500) + hi;
            u[(size_t)(rb0 * NN + m) * HH + j] = g;
        }
    } else {
#pragma unroll
        for (int r = 0; r < 16; r++) {
            int row = row0 + r;
            int rb = row / NN, rn = row % NN;
            float g = sigmoidf_(acc[r] + bias);
            if (rn < 500) {
                int m = 2 * rn + hi;
                GB[(size_t)(rb * CC + 1 + j) * KP + m] = (__bf16)(g * h[(size_t)(rb * NN + m) * HH + j]);
            } else {
                int m = 2 * (rn - 500) + hi;
                u[(size_t)(rb * NN + m) * HH + j] = g;
            }
        }
    }
}

// ---------------- cell finish + residual + LN + mean; write h into Gl (bf16), x-cols ----------------
__global__ __launch_bounds__(256) void k_cellfinish(const float* __restrict__ acT,
                                                    const float* __restrict__ w2,
                                                    const float* __restrict__ b2,
                                                    const float* __restrict__ u,
                                                    float* __restrict__ h,
                                                    const float* __restrict__ x_in,
                                                    const float* __restrict__ res_w,
                                                    const float* __restrict__ res_b,
                                                    const float* __restrict__ ln_g,
                                                    const float* __restrict__ ln_b,
                                                    float* __restrict__ x_out,
                                                    float* __restrict__ out_t,
                                                    int store_out,
                                                    __bf16* __restrict__ Gl,
                                                    __bf16* __restrict__ gx1,
                                                    __bf16* __restrict__ gx2) {
    __shared__ float s_ac[16][132];
    __shared__ float s_y[16][128];
    __shared__ float s_hn[16][130];
    __shared__ float s_stat[16][2];
    int row0 = blockIdx.x * 16;
    int t = threadIdx.x;
    for (int q = t; q < 16 * CC; q += 256) {
        int c = q >> 4, r = q & 15;
        int row = row0 + r;
        int rb = row / NN, rn = row % NN;
        s_ac[r][c] = acT[(size_t)(rb * CC + c) * MP + rn];
    }
    __syncthreads();
    int j = t & 127, half = t >> 7;
    float acc[8];
#pragma unroll
    for (int r = 0; r < 8; r++) acc[r] = 0.f;
    for (int c = 0; c < CC; c++) {
        float w = w2[c * HH + j];
#pragma unroll
        for (int r = 0; r < 8; r++) acc[r] += s_ac[half * 8 + r][c] * w;
    }
    float bias = b2[j];
    float rw = res_w[j], rbv = res_b[j];
#pragma unroll
    for (int r = 0; r < 8; r++) {
        int rr = half * 8 + r;
        int row = row0 + rr;
        float cv = tanhf(acc[r] + bias);
        float uu = u[(size_t)row * HH + j];
        float hv = h[(size_t)row * HH + j];
        float hn = uu * hv + (1.f - uu) * cv;
        h[(size_t)row * HH + j] = hn;
        s_hn[rr][j] = hn;
        s_y[rr][j] = hn + x_in[row] * rw + rbv;
    }
    __syncthreads();
    int wave = t >> 6, lane = t & 63;
    for (int rr = wave; rr < 16; rr += 4) {
        float v1 = s_y[rr][lane], v2 = s_y[rr][lane + 64];
        float s = v1 + v2, ss = v1 * v1 + v2 * v2;
        for (int off = 32; off > 0; off >>= 1) { s += __shfl_down(s, off); ss += __shfl_down(ss, off); }
        if (lane == 0) {
            float mu = s * (1.f / 128.f);
            float var = ss * (1.f / 128.f) - mu * mu;
            s_stat[rr][0] = mu;
            s_stat[rr][1] = rsqrtf(var + 1e-5f);
        }
    }
    __syncthreads();
    float lg = ln_g[j], lb = ln_b[j];
    float outv[8];
#pragma unroll
    for (int r = 0; r < 8; r++) {
        int rr = half * 8 + r;
        outv[r] = (s_y[rr][j] - s_stat[rr][0]) * s_stat[rr][1] * lg + lb;
    }
    __syncthreads();
#pragma unroll
    for (int r = 0; r < 8; r++) s_y[half * 8 + r][j] = outv[r];
    __syncthreads();
    for (int rr = wave; rr < 16; rr += 4) {
        float v = s_y[rr][lane] + s_y[rr][lane + 64];
        for (int off = 32; off > 0; off >>= 1) v += __shfl_down(v, off);
        if (lane == 0) {
            float xv = v * (1.f / 128.f);
            int row = row0 + rr;
            x_out[row] = xv;
            int rb = row / NN, rn = row % NN;
            __bf16 bv = (__bf16)xv;
            gx1[(size_t)(rb * CC) * KP + rn] = bv;
            if (gx2) gx2[(size_t)(rb * CC) * KP + rn] = bv;
        }
    }
    if (store_out) {
#pragma unroll
        for (int r = 0; r < 8; r++) {
            int rr = half * 8 + r;
            out_t[(size_t)(row0 + rr) * HH + j] = outv[r];
        }
    }
    // write updated h into this layer's G buffer (bf16, transposed), for next timestep
    int rb0 = row0 / NN, rn0 = row0 % NN;
    if ((rn0 + 15) < NN) {
        int jj = t >> 1, hf = t & 1;
        bf16x8 v;
#pragma unroll
        for (int q = 0; q < 8; q++) v[q] = (__bf16)s_hn[hf * 8 + q][jj];
        *(bf16x8*)(Gl + (size_t)(rb0 * CC + 1 + jj) * KP + rn0 + hf * 8) = v;
    } else {
#pragma unroll
        for (int r = 0; r < 8; r++) {
            int rr = half * 8 + r;
            int row = row0 + rr;
            int rb = row / NN, rn = row % NN;
            Gl[(size_t)(rb * CC + 1 + j) * KP + rn] = (__bf16)s_hn[rr][j];
        }
    }
}

// ---------------- fused GRU cell (coalesced transposed weights) ----------------
__global__ __launch_bounds__(128) void k_gru(const float* __restrict__ xin,
                                             float* __restrict__ hg,
                                             const float* __restrict__ wT,
                                             const float* __restrict__ bih,
                                             const float* __restrict__ bhh) {
    __shared__ float s_x[8][128];
    __shared__ float s_h[8][128];
    int row0 = blockIdx.x * 8;
    int t = threadIdx.x;
    for (int q = t; q < 8 * HH; q += 128) {
        int r = q >> 7, c = q & 127;
        s_x[r][c] = xin[(size_t)(row0 + r) * HH + c];
        s_h[r][c] = hg[(size_t)(row0 + r) * HH + c];
    }
    __syncthreads();
    float gi0[8], gi1[8], gi2[8], gh0[8], gh1[8], gh2[8];
#pragma unroll
    for (int r = 0; r < 8; r++) { gi0[r]=gi1[r]=gi2[r]=gh0[r]=gh1[r]=gh2[r]=0.f; }
    const float* wi = wT;
    const float* wh = wT + 128 * 384;
    for (int c = 0; c < HH; c++) {
        float wi0 = wi[c * 384 + t], wi1 = wi[c * 384 + 128 + t], wi2 = wi[c * 384 + 256 + t];
        float wh0 = wh[c * 384 + t], wh1 = wh[c * 384 + 128 + t], wh2 = wh[c * 384 + 256 + t];
#pragma unroll
        for (int r = 0; r < 8; r++) {
            float xv = s_x[r][c], hv = s_h[r][c];
            gi0[r] += xv * wi0; gi1[r] += xv * wi1; gi2[r] += xv * wi2;
            gh0[r] += hv * wh0; gh1[r] += hv * wh1; gh2[r] += hv * wh2;
        }
    }
    float bi0 = bih[t], bi1 = bih[t + 128], bi2 = bih[t + 256];
    float bh0 = bhh[t], bh1 = bhh[t + 128], bh2 = bhh[t + 256];
#pragma unroll
    for (int r = 0; r < 8; r++) {
        float rg = sigmoidf_(gi0[r] + bi0 + gh0[r] + bh0);
        float zg = sigmoidf_(gi1[r] + bi1 + gh1[r] + bh1);
        float ng = tanhf(gi2[r] + bi2 + rg * (gh2[r] + bh2));
        hg[(size_t)(row0 + r) * HH + t] = (1.f - zg) * ng + zg * s_h[r][t];
    }
}

// ---------------- head: proj -> relu MLP -> out ----------------
__global__ __launch_bounds__(256) void k_head(const float* __restrict__ hg,
                                              const float* __restrict__ pw,
                                              const float* __restrict__ pb,
                                              const float* __restrict__ w1,
                                              const float* __restrict__ b1,
                                              const float* __restrict__ w2,
                                              const float* __restrict__ b2,
                                              float* __restrict__ out) {
    __shared__ float s_h[16][128];
    __shared__ float s_last[16][128];
    __shared__ float s_hid[16][256];
    int row0 = blockIdx.x * 16;
    int t = threadIdx.x;
    for (int q = t; q < 16 * HH; q += 256) {
        int r = q >> 7, c = q & 127;
        s_h[r][c] = hg[(size_t)(row0 + r) * HH + c];
    }
    __syncthreads();
    int j = t & 127, half = t >> 7;
    float acc[8];
#pragma unroll
    for (int r = 0; r < 8; r++) acc[r] = 0.f;
    for (int c = 0; c < HH; c++) {
        float w = pw[j * HH + c];
#pragma unroll
        for (int r = 0; r < 8; r++) acc[r] += s_h[half * 8 + r][c] * w;
    }
    float pbv = pb[j];
#pragma unroll
    for (int r = 0; r < 8; r++) s_last[half * 8 + r][j] = acc[r] + pbv;
    __syncthreads();
    float acc2[16];
#pragma unroll
    for (int r = 0; r < 16; r++) acc2[r] = 0.f;
    for (int c = 0; c < HH; c++) {
        float w = w1[t * HH + c];
#pragma unroll
        for (int r = 0; r < 16; r++) acc2[r] += s_last[r][c] * w;
    }
    float b1v = b1[t];
#pragma unroll
    for (int r = 0; r < 16; r++) s_hid[r][t] = fmaxf(acc2[r] + b1v, 0.f);
    __syncthreads();
    float acc3[8];
#pragma unroll
    for (int r = 0; r < 8; r++) acc3[r] = 0.f;
    for (int c = 0; c < 256; c++) {
        float w = w2[j * 256 + c];
#pragma unroll
        for (int r = 0; r < 8; r++) acc3[r] += s_hid[half * 8 + r][c] * w;
    }
    float b2v = b2[j];
#pragma unroll
    for (int r = 0; r < 8; r++) out[(size_t)(row0 + half * 8 + r) * HH + j] = acc3[r] + b2v;
}

extern "C" void kernel_launch(void* const* d_in, const int* in_sizes, int n_in,
                              void* d_out, int out_size, void* d_ws, size_t ws_size,
                              hipStream_t stream) {
    const float* inp    = (const float*)d_in[0];
    const float* adj    = (const float*)d_in[1];
    const float* gc1_w  = (const float*)d_in[2];
    const float* gc1_b  = (const float*)d_in[3];
    const float* gc2_w  = (const float*)d_in[4];
    const float* gc2_b  = (const float*)d_in[5];
    const float* ln_g   = (const float*)d_in[6];
    const float* ln_b   = (const float*)d_in[7];
    const float* res_w  = (const float*)d_in[8];
    const float* res_b  = (const float*)d_in[9];
    const float* wih    = (const float*)d_in[10];
    const float* whh    = (const float*)d_in[11];
    const float* bih    = (const float*)d_in[12];
    const float* bhh    = (const float*)d_in[13];
    const float* proj_w = (const float*)d_in[14];
    const float* proj_b = (const float*)d_in[15];
    const float* ow1    = (const float*)d_in[16];
    const float* ob1    = (const float*)d_in[17];
    const float* ow2    = (const float*)d_in[18];
    const float* ob2    = (const float*)d_in[19];
    float* out = (float*)d_out;

    char* ws = (char*)d_ws;
    size_t off = 0;
    __bf16* Lb = (__bf16*)(ws + off); off += (size_t)MP * KP * 2;         // 2 MB
    __bf16* Gg0 = (__bf16*)(ws + off); off += (size_t)GRP * KP * 2;       // 4.46 MB
    __bf16* Gg1 = (__bf16*)(ws + off); off += (size_t)GRP * KP * 2;
    __bf16* GB  = (__bf16*)(ws + off); off += (size_t)GRP * KP * 2;
    float* acT  = (float*)(ws + off);  off += (size_t)GRP * MP * 4;       // 8.9 MB
    float* u    = (float*)(ws + off);  off += (size_t)NROW * HH * 4;
    float* h0   = (float*)(ws + off);  off += (size_t)NROW * HH * 4;
    float* h1   = (float*)(ws + off);  off += (size_t)NROW * HH * 4;
    float* outT = (float*)(ws + off);  off += (size_t)NROW * HH * 4;
    float* hg   = (float*)(ws + off);  off += (size_t)NROW * HH * 4;
    float* xA   = (float*)(ws + off);  off += (size_t)NROW * 4;
    float* xB   = (float*)(ws + off);  off += (size_t)NROW * 4;
    float* wT   = (float*)(ws + off);  off += (size_t)2 * 128 * 384 * 4;
    float* a_sm = acT;  // overlay: softmax scratch only used before first GEMM

    size_t stBytes = (size_t)NROW * HH * 4;
    hipMemsetAsync(Lb, 0, (size_t)MP * KP * 2, stream);
    hipMemsetAsync(Gg0, 0, (size_t)GRP * KP * 2 * 3, stream);   // Gg0,Gg1,GB contiguous
    hipMemsetAsync(h0, 0, stBytes, stream);
    hipMemsetAsync(h1, 0, stBytes, stream);
    hipMemsetAsync(hg, 0, stBytes, stream);

    k_softmax<<<NN, 256, 0, stream>>>(adj, a_sm);
    k_build_Lt<<<dim3(16, 16), 256, 0, stream>>>(a_sm, Lb);
    k_transpose_w<<<192, 256, 0, stream>>>(wih, whh, wT);

    dim3 ggrid(16, 17);
    for (int t = 0; t < TT; t++) {
        k_copy_x<<<63, 256, 0, stream>>>(inp, xA, Gg0, GB, t);
        // layer 0
        k_gemm_mfma<<<ggrid, 256, 0, stream>>>(Gg0, Lb, acT);
        k_gates<<<1000, 256, 0, stream>>>(acT, gc1_w, gc1_b, h0, GB, u);
        k_gemm_mfma<<<ggrid, 256, 0, stream>>>(GB, Lb, acT);
        k_cellfinish<<<1000, 256, 0, stream>>>(acT, gc2_w, gc2_b, u, h0, xA,
                                               res_w, res_b, ln_g, ln_b, xB, outT, 0,
                                               Gg0, Gg1, GB);
        // layer 1
        k_gemm_mfma<<<ggrid, 256, 0, stream>>>(Gg1, Lb, acT);
        k_gates<<<1000, 256, 0, stream>>>(acT, gc1_w + (size_t)CC * G2, gc1_b + G2, h1, GB, u);
        k_gemm_mfma<<<ggrid, 256, 0, stream>>>(GB, Lb, acT);
        k_cellfinish<<<1000, 256, 0, stream>>>(acT, gc2_w + (size_t)CC * HH, gc2_b + HH, u, h1, xB,
                                               res_w, res_b, ln_g + HH, ln_b + HH, xA, outT, 1,
                                               Gg1, Gg0, (__bf16*)nullptr);
        k_gru<<<2000, 128, 0, stream>>>(outT, hg, wT, bih, bhh);
    }
    k_head<<<1000, 256, 0, stream>>>(hg, proj_w, proj_b, ow1, ob1, ow2, ob2, out);
}